// Round 4
// baseline (813.817 us; speedup 1.0000x reference)
//
#include <hip/hip_runtime.h>
#include <stdint.h>
#include <stddef.h>

// ---------------- Problem constants ----------------
#define NN 16384
#define FF 39
#define VV 50000
#define EE 64
#define K1 2496   // FF*EE
#define H1 1024
#define H2 512
#define H3 256
#define BN_EPS 1e-5f

typedef __attribute__((ext_vector_type(8))) short bf16x8;
typedef __attribute__((ext_vector_type(4))) float f32x4;
typedef unsigned short u16;

__device__ __forceinline__ float bf2f(u16 u) {
    unsigned int x = ((unsigned int)u) << 16;
    return __builtin_bit_cast(float, x);
}
__device__ __forceinline__ u16 f2bf(float f) {
    unsigned int x = __builtin_bit_cast(unsigned int, f);
    x += 0x7fffu + ((x >> 16) & 1u);   // round-to-nearest-even
    return (u16)(x >> 16);
}

// Async global->LDS 16B copy: LDS dest = wave-uniform base + lane*16.
__device__ __forceinline__ void async_copy16(const void* gp, void* lp) {
    __builtin_amdgcn_global_load_lds(
        (const __attribute__((address_space(1))) void*)(uintptr_t)gp,
        (__attribute__((address_space(3))) void*)(uintptr_t)lp,
        16, 0, 0);
}

// ---------------- Prep kernel ----------------
// blocks [0, 4096): embedding gather + FM terms (one wave per sample).
//   block 0 additionally zeroes the BN-stat accumulators (replaces memset).
// blocks [4096, 7232): batched weight transpose f32[K][N] -> bf16[N][K].
__global__ __launch_bounds__(256) void prep_kernel(
    const int* __restrict__ Xi, const float* __restrict__ Xv,
    const float* __restrict__ W1, const float* __restrict__ W2,
    u16* __restrict__ deep, float* __restrict__ fm_part,
    const float* __restrict__ lw1, const float* __restrict__ lw2,
    const float* __restrict__ lw3,
    u16* __restrict__ lw1T, u16* __restrict__ lw2T, u16* __restrict__ lw3T,
    float* __restrict__ stats0)
{
    __shared__ float tile[32][33];
    int bid = blockIdx.x;

    if (bid < NN / 4) {
        // ---- embedding + FM path ----
        if (bid == 0) {
            for (int i = threadIdx.x; i < 3584; i += 256) stats0[i] = 0.f;
        }
        int wave = threadIdx.x >> 6, lane = threadIdx.x & 63;
        int n = bid * 4 + wave;

        int   idx_l = 0; float xv_l = 0.f, e1 = 0.f;
        if (lane < FF) {
            idx_l = Xi[n * FF + lane];
            xv_l  = Xv[n * FF + lane];
            e1    = W1[(size_t)lane * VV + idx_l] * xv_l;
        }
        int fq = lane >> 4, eq = lane & 15;
        float s0 = 0.f, s1 = 0.f, s2 = 0.f, s3 = 0.f;
        float q0 = 0.f, q1 = 0.f, q2 = 0.f, q3 = 0.f;
        u16* drow = deep + (size_t)n * K1;

        #pragma unroll
        for (int g = 0; g < 10; ++g) {
            int f = g * 4 + fq;
            bool valid = (f < FF);
            int fs = valid ? f : 0;
            int   idx = __shfl(idx_l, fs);
            float xv  = __shfl(xv_l, fs);
            float4 v4 = make_float4(0.f, 0.f, 0.f, 0.f);
            if (valid)
                v4 = *(const float4*)(W2 + ((size_t)f * VV + idx) * EE + eq * 4);
            v4.x *= xv; v4.y *= xv; v4.z *= xv; v4.w *= xv;
            s0 += v4.x; q0 += v4.x * v4.x;
            s1 += v4.y; q1 += v4.y * v4.y;
            s2 += v4.z; q2 += v4.z * v4.z;
            s3 += v4.w; q3 += v4.w * v4.w;
            if (valid) {
                union { u16 u[4]; uint2 d; } pk;
                pk.u[0] = f2bf(v4.x); pk.u[1] = f2bf(v4.y);
                pk.u[2] = f2bf(v4.z); pk.u[3] = f2bf(v4.w);
                *(uint2*)(drow + f * EE + eq * 4) = pk.d;
            }
        }
        s0 += __shfl_xor(s0, 16); s0 += __shfl_xor(s0, 32);
        s1 += __shfl_xor(s1, 16); s1 += __shfl_xor(s1, 32);
        s2 += __shfl_xor(s2, 16); s2 += __shfl_xor(s2, 32);
        s3 += __shfl_xor(s3, 16); s3 += __shfl_xor(s3, 32);
        q0 += __shfl_xor(q0, 16); q0 += __shfl_xor(q0, 32);
        q1 += __shfl_xor(q1, 16); q1 += __shfl_xor(q1, 32);
        q2 += __shfl_xor(q2, 16); q2 += __shfl_xor(q2, 32);
        q3 += __shfl_xor(q3, 16); q3 += __shfl_xor(q3, 32);

        float fm2 = 0.5f * ((s0 * s0 + s1 * s1 + s2 * s2 + s3 * s3)
                            - (q0 + q1 + q2 + q3));
        float t = e1 + ((fq == 0) ? fm2 : 0.f);
        #pragma unroll
        for (int off = 32; off; off >>= 1) t += __shfl_xor(t, off);
        if (lane == 0) fm_part[n] = t;
        return;
    }

    // ---- transpose path ----
    int tb = bid - NN / 4;
    const float* w; u16* wT; int K, Nc, bx, by;
    if (tb < 2496)      { w = lw1; wT = lw1T; K = K1; Nc = H1; bx = tb & 31; by = tb >> 5; }
    else if (tb < 3008) { tb -= 2496; w = lw2; wT = lw2T; K = H1; Nc = H2; bx = tb & 15; by = tb >> 4; }
    else                { tb -= 3008; w = lw3; wT = lw3T; K = H2; Nc = H3; bx = tb & 7;  by = tb >> 3; }

    int tx = threadIdx.x & 31, ty = threadIdx.x >> 5;
    #pragma unroll
    for (int j = 0; j < 4; ++j) {
        int y = by * 32 + ty + j * 8;
        tile[ty + j * 8][tx] = w[(size_t)y * Nc + bx * 32 + tx];
    }
    __syncthreads();
    int xo = by * 32 + tx;
    #pragma unroll
    for (int j = 0; j < 4; ++j) {
        int yo = bx * 32 + ty + j * 8;
        wT[(size_t)yo * K + xo] = f2bf(tile[tx][ty + j * 8]);
    }
}

// ============ gemm1: 256x256xBK64, 8 waves, counted-vmcnt pipeline ==========
// Layer-1 GEMM (no BN on input). LDS 128 KiB, double-buffered.
// FRAGMENT-CONTIGUOUS LDS layout: lane l stages global (row = l&15,
// 16B-chunk = l>>4), so each 1024B staged block is stored in exact MFMA
// fragment order [kq][r16]. Every ds_read_b128 is then base + lane*16 —
// contiguous 1024B per wave = zero bank conflicts (no XOR swizzle needed;
// the 64B-row-stride XOR variant only permutes within the same bank set).
// Pipeline (T3/T4): stage K-tile t+2 after the barrier that closes all reads
// of buf[t&1]; s_waitcnt vmcnt(8) keeps those 8 loads in flight across the
// barrier while guaranteeing (in-order vmem retirement) K-tile t+1 landed.
// Raw s_barrier only — __syncthreads would drain vmcnt to 0.
__global__ __launch_bounds__(512, 2) void gemm1_kernel(
    const u16* __restrict__ A, const u16* __restrict__ Bt,
    const float* __restrict__ lb, u16* __restrict__ C,
    float* __restrict__ colsum, float* __restrict__ colsq,
    int Nc, int K)
{
    __shared__ __align__(16) short SH[65536];   // A:[0,32768) B:[32768,65536) shorts

    int tid = threadIdx.x;
    int w = tid >> 6, l = tid & 63;
    int wm = w >> 2, wn = w & 3;            // 2 (M) x 4 (N) wave grid
    int r16 = l & 15;

    // XCD-aware bijective swizzle (nwg = 256, %8 == 0)
    unsigned nwg  = gridDim.x * gridDim.y;
    unsigned orig = blockIdx.y * gridDim.x + blockIdx.x;
    unsigned wg   = (orig & 7u) * (nwg >> 3) + (orig >> 3);
    unsigned bx   = wg % gridDim.x, by = wg / gridDim.x;
    int mBase = by * 256, nBase = bx * 256;

    // ---- staging geometry (fragment-order): row-in-group = l&15, chunk = l>>4
    const u16* gA = A  + (size_t)(mBase + w * 16 + (l & 15)) * K + (l >> 4) * 8;
    const u16* gB = Bt + (size_t)(nBase + w * 16 + (l & 15)) * K + (l >> 4) * 8;
    int dstW = w * 512;                     // wave-uniform LDS base (shorts)

    // ---- fragment-read geometry: lane-linear within each 512-short group
    int aoff = wm * 4096 + l * 8;           // + mi*512 + ks*8192
    int boff = 32768 + wn * 2048 + l * 8;   // + ni*512 + ks*8192

    f32x4 acc[8][4];
    #pragma unroll
    for (int mi = 0; mi < 8; ++mi)
        #pragma unroll
        for (int ni = 0; ni < 4; ++ni)
            acc[mi][ni] = (f32x4){0.f, 0.f, 0.f, 0.f};

    const int nt = K / 64;                  // 39

    // stage one full K-tile (8 async issues per thread)
    auto stage = [&](int kt, int b) {
        const u16* ga = gA + (size_t)kt * 64;
        const u16* gb = gB + (size_t)kt * 64;
        short* baseA = SH + b * 16384;
        short* baseB = SH + 32768 + b * 16384;
        async_copy16(ga,                         baseA + dstW);          // kh0 half0
        async_copy16(ga + (size_t)128 * K,       baseA + 4096 + dstW);   // kh0 half1
        async_copy16(ga + 32,                    baseA + 8192 + dstW);   // kh1 half0
        async_copy16(ga + (size_t)128 * K + 32,  baseA + 12288 + dstW);  // kh1 half1
        async_copy16(gb,                         baseB + dstW);
        async_copy16(gb + (size_t)128 * K,       baseB + 4096 + dstW);
        async_copy16(gb + 32,                    baseB + 8192 + dstW);
        async_copy16(gb + (size_t)128 * K + 32,  baseB + 12288 + dstW);
    };

    // prologue: fill both buffers, wait for K-tile 0 (oldest 8 of 16)
    stage(0, 0);
    stage(1, 1);
    asm volatile("s_waitcnt vmcnt(8)" ::: "memory");
    __builtin_amdgcn_s_barrier();

    for (int t = 0; t < nt; ++t) {
        int b = t & 1;
        const short* pa = SH + b * 16384 + aoff;
        const short* pb = SH + b * 16384 + boff;
        #pragma unroll
        for (int ks = 0; ks < 2; ++ks) {
            bf16x8 af[8], bf[4];
            #pragma unroll
            for (int mi = 0; mi < 8; ++mi)
                af[mi] = *(const bf16x8*)(pa + ks * 8192 + mi * 512);
            #pragma unroll
            for (int ni = 0; ni < 4; ++ni)
                bf[ni] = *(const bf16x8*)(pb + ks * 8192 + ni * 512);
            __builtin_amdgcn_s_setprio(1);
            #pragma unroll
            for (int mi = 0; mi < 8; ++mi)
                #pragma unroll
                for (int ni = 0; ni < 4; ++ni)
                    acc[mi][ni] = __builtin_amdgcn_mfma_f32_16x16x32_bf16(
                        af[mi], bf[ni], acc[mi][ni], 0, 0, 0);
            __builtin_amdgcn_s_setprio(0);
        }
        // close all reads of buf b (all waves) before overwriting it
        asm volatile("s_waitcnt lgkmcnt(0)" ::: "memory");
        __builtin_amdgcn_sched_barrier(0);
        __builtin_amdgcn_s_barrier();
        if (t + 2 < nt) {
            stage(t + 2, b);
            asm volatile("s_waitcnt vmcnt(8)" ::: "memory");   // K-tile t+1 landed
        } else {
            asm volatile("s_waitcnt vmcnt(0)" ::: "memory");   // drain tail
        }
        __builtin_amdgcn_sched_barrier(0);
        __builtin_amdgcn_s_barrier();
    }

    // epilogue: bias, bf16 store (pre-BN), column sum/sumsq partials
    int quad = l >> 4;
    #pragma unroll
    for (int ni = 0; ni < 4; ++ni) {
        int col = nBase + wn * 64 + ni * 16 + r16;
        float lbv = lb[col];
        float csum = 0.f, csq = 0.f;
        #pragma unroll
        for (int mi = 0; mi < 8; ++mi) {
            int row0 = mBase + wm * 128 + mi * 16 + quad * 4;
            f32x4 v = acc[mi][ni];
            #pragma unroll
            for (int r = 0; r < 4; ++r) {
                float x = v[r] + lbv;
                C[(size_t)(row0 + r) * Nc + col] = f2bf(x);
                csum += x;
                csq  += x * x;
            }
        }
        csum += __shfl_xor(csum, 16); csum += __shfl_xor(csum, 32);
        csq  += __shfl_xor(csq, 16);  csq  += __shfl_xor(csq, 32);
        if (quad == 0) {
            atomicAdd(&colsum[col], csum);
            atomicAdd(&colsq[col],  csq);
        }
    }
}

// ---------------- bf16 MFMA GEMM with fused BN-stat partials ----------------
// (layers 2/3) 128x128x32 tile, 4 waves, m97 structure. APPLY_BN=1 applies
// relu(x*scA+shA) during reg-staging of A. Kept for gemm2/3 where the 256^2
// tile would idle 50-75% of CUs.
#define BM 128
#define BNT 128
#define BK 32

template<int APPLY_BN>
__global__ __launch_bounds__(256, 3) void gemm_bn_kernel(
    const u16* __restrict__ A, const u16* __restrict__ Bt,
    const float* __restrict__ lb, u16* __restrict__ C,
    float* __restrict__ colsum, float* __restrict__ colsq,
    const float* __restrict__ scA, const float* __restrict__ shA,
    int Nc, int K)
{
    __shared__ __align__(16) short As[BM * BK];
    __shared__ __align__(16) short Bs[BNT * BK];

    int tid  = threadIdx.x;
    int wave = tid >> 6, lane = tid & 63;
    int wm = wave >> 1, wn = wave & 1;

    unsigned nwg  = gridDim.x * gridDim.y;
    unsigned orig = blockIdx.y * gridDim.x + blockIdx.x;
    unsigned wg   = (orig & 7u) * (nwg >> 3) + (orig >> 3);
    unsigned bx   = wg % gridDim.x, by = wg / gridDim.x;
    int mBase = by * BM, nBase = bx * BNT;

    int rowA = tid >> 2;
    int ca   = (tid & 3) * 8;
    const u16* gA0 = A  + (size_t)(mBase + rowA) * K + ca;
    const u16* gA1 = gA0 + (size_t)64 * K;
    const u16* gB0 = Bt + (size_t)(nBase + rowA) * K + ca;
    const u16* gB1 = gB0 + (size_t)64 * K;

    short* lA0 = As + wave * 512;
    short* lA1 = As + 2048 + wave * 512;
    short* lB0 = Bs + wave * 512;
    short* lB1 = Bs + 2048 + wave * 512;

    f32x4 acc[4][4];
    #pragma unroll
    for (int mi = 0; mi < 4; ++mi)
        #pragma unroll
        for (int ni = 0; ni < 4; ++ni)
            acc[mi][ni] = (f32x4){0.f, 0.f, 0.f, 0.f};

    int r16 = lane & 15, kq = lane >> 4;
    const short* fA = &As[(wm * 64 + r16) * BK + kq * 8];
    const short* fB = &Bs[(wn * 64 + r16) * BK + kq * 8];

    int kcur = ca;
    for (int kiter = K / BK; kiter > 0; --kiter) {
        __syncthreads();
        if constexpr (APPLY_BN) {
            int4 ra0 = *(const int4*)gA0;
            int4 ra1 = *(const int4*)gA1;
            async_copy16(gB0, lB0);
            async_copy16(gB1, lB1);
            float sc[8], sh[8];
            #pragma unroll
            for (int j = 0; j < 8; ++j) { sc[j] = scA[kcur + j]; sh[j] = shA[kcur + j]; }
            union { u16 u[8]; int4 d; } in, outp;
            in.d = ra0;
            #pragma unroll
            for (int j = 0; j < 8; ++j)
                outp.u[j] = f2bf(fmaxf(bf2f(in.u[j]) * sc[j] + sh[j], 0.f));
            *(int4*)(As + (size_t)tid * 8) = outp.d;
            in.d = ra1;
            #pragma unroll
            for (int j = 0; j < 8; ++j)
                outp.u[j] = f2bf(fmaxf(bf2f(in.u[j]) * sc[j] + sh[j], 0.f));
            *(int4*)(As + 2048 + (size_t)tid * 8) = outp.d;
            kcur += BK;
        } else {
            async_copy16(gA0, lA0);
            async_copy16(gA1, lA1);
            async_copy16(gB0, lB0);
            async_copy16(gB1, lB1);
        }
        gA0 += BK; gA1 += BK; gB0 += BK; gB1 += BK;
        __syncthreads();

        bf16x8 af[4], bfr[4];
        #pragma unroll
        for (int mi = 0; mi < 4; ++mi)
            af[mi] = *(const bf16x8*)(fA + mi * 16 * BK);
        #pragma unroll
        for (int ni = 0; ni < 4; ++ni)
            bfr[ni] = *(const bf16x8*)(fB + ni * 16 * BK);
        #pragma unroll
        for (int mi = 0; mi < 4; ++mi)
            #pragma unroll
            for (int ni = 0; ni < 4; ++ni)
                acc[mi][ni] = __builtin_amdgcn_mfma_f32_16x16x32_bf16(
                    af[mi], bfr[ni], acc[mi][ni], 0, 0, 0);
    }

    int quad = lane >> 4;
    #pragma unroll
    for (int ni = 0; ni < 4; ++ni) {
        int col = nBase + wn * 64 + ni * 16 + r16;
        float lbv = lb[col];
        float csum = 0.f, csq = 0.f;
        #pragma unroll
        for (int mi = 0; mi < 4; ++mi) {
            int row0 = mBase + wm * 64 + mi * 16 + quad * 4;
            f32x4 v = acc[mi][ni];
            #pragma unroll
            for (int r = 0; r < 4; ++r) {
                float x = v[r] + lbv;
                C[(size_t)(row0 + r) * Nc + col] = f2bf(x);
                csum += x;
                csq  += x * x;
            }
        }
        csum += __shfl_xor(csum, 16); csum += __shfl_xor(csum, 32);
        csq  += __shfl_xor(csq, 16);  csq  += __shfl_xor(csq, 32);
        if (quad == 0) {
            atomicAdd(&colsum[col], csum);
            atomicAdd(&colsq[col],  csq);
        }
    }
}

// ---------------- BN finalize: per-column scale/shift ----------------
__global__ void bn_finalize_kernel(const float* __restrict__ colsum,
                                   const float* __restrict__ colsq,
                                   const float* __restrict__ g,
                                   const float* __restrict__ b,
                                   float* __restrict__ scale,
                                   float* __restrict__ shift, int Nc)
{
    int c = blockIdx.x * blockDim.x + threadIdx.x;
    if (c >= Nc) return;
    const float invN = 1.0f / (float)NN;
    float mean = colsum[c] * invN;
    float var  = colsq[c] * invN - mean * mean;
    float sc   = g[c] * rsqrtf(var + BN_EPS);
    scale[c] = sc;
    shift[c] = b[c] - mean * sc;
}

// ------- Final: inline BN finalize (layer3) + ReLU + row sum + FM + bias ----
__global__ __launch_bounds__(256) void final_kernel(
    const u16* __restrict__ pre3,
    const float* __restrict__ colsum, const float* __restrict__ colsq,
    const float* __restrict__ g, const float* __restrict__ b,
    const float* __restrict__ fm_part,
    const float* __restrict__ bias, float* __restrict__ out)
{
    int wave = threadIdx.x >> 6, lane = threadIdx.x & 63;
    int n = blockIdx.x * 4 + wave;
    const float invN = 1.0f / (float)NN;
    float s = 0.f;
    #pragma unroll
    for (int q = 0; q < 4; ++q) {
        int c = q * 64 + lane;
        float mean = colsum[c] * invN;
        float var  = colsq[c] * invN - mean * mean;
        float sc   = g[c] * rsqrtf(var + BN_EPS);
        float sh   = b[c] - mean * sc;
        float x = bf2f(pre3[(size_t)n * H3 + c]);
        s += fmaxf(x * sc + sh, 0.f);
    }
    #pragma unroll
    for (int off = 32; off; off >>= 1) s += __shfl_xor(s, off);
    if (lane == 0) out[n] = s + fm_part[n] + bias[0];
}

// ---------------- Host launcher ----------------
extern "C" void kernel_launch(void* const* d_in, const int* in_sizes, int n_in,
                              void* d_out, int out_size, void* d_ws, size_t ws_size,
                              hipStream_t stream)
{
    const int*   Xi   = (const int*)d_in[0];
    const float* Xv   = (const float*)d_in[1];
    const float* W1   = (const float*)d_in[2];
    const float* W2   = (const float*)d_in[3];
    const float* bias = (const float*)d_in[4];
    const float* lw1  = (const float*)d_in[5];
    const float* lb1  = (const float*)d_in[6];
    const float* g1   = (const float*)d_in[7];
    const float* b1   = (const float*)d_in[8];
    const float* lw2  = (const float*)d_in[9];
    const float* lb2  = (const float*)d_in[10];
    const float* g2   = (const float*)d_in[11];
    const float* b2   = (const float*)d_in[12];
    const float* lw3  = (const float*)d_in[13];
    const float* lb3  = (const float*)d_in[14];
    const float* g3   = (const float*)d_in[15];
    const float* b3   = (const float*)d_in[16];
    float* out = (float*)d_out;
    char*  ws  = (char*)d_ws;

    // ---- workspace layout (bytes, 256-aligned) ----
    float* fm_part = (float*)(ws + 0);                  // 65536
    float* stats0  = (float*)(ws + 65536);              // colsum/colsq block
    float* colsum1 = (float*)(ws + 65536);
    float* colsq1  = (float*)(ws + 69632);
    float* colsum2 = (float*)(ws + 73728);
    float* colsq2  = (float*)(ws + 75776);
    float* colsum3 = (float*)(ws + 77824);
    float* colsq3  = (float*)(ws + 78848);
    float* scale1  = (float*)(ws + 79872);
    float* shift1  = (float*)(ws + 83968);
    float* scale2  = (float*)(ws + 88064);
    float* shift2  = (float*)(ws + 90112);
    u16* lw1T = (u16*)(ws + 94208);                     // 5,111,808
    u16* lw2T = (u16*)(ws + 5206016);                   // 1,048,576
    u16* lw3T = (u16*)(ws + 6254592);                   // 262,144
    u16* pre1 = (u16*)(ws + 6516736);                   // 33,554,432
    u16* deep = (u16*)(ws + 40071168);                  // 81,788,928
    u16* pre2 = (u16*)(ws + 40071168);                  // reuse deep region
    u16* pre3 = (u16*)(ws + 56848384);

    // prep: embed+FM (4096 blocks) | 3 weight transposes (3136) | stat zeroing
    prep_kernel<<<NN / 4 + 3136, 256, 0, stream>>>(
        Xi, Xv, W1, W2, deep, fm_part, lw1, lw2, lw3, lw1T, lw2T, lw3T, stats0);

    // layer 1: 256^2 counted-vmcnt pipeline (grid 4 x 64 = 256 blocks)
    gemm1_kernel<<<dim3(H1 / 256, NN / 256), 512, 0, stream>>>(
        deep, lw1T, lb1, pre1, colsum1, colsq1, H1, K1);
    bn_finalize_kernel<<<H1 / 256, 256, 0, stream>>>(colsum1, colsq1, g1, b1, scale1, shift1, H1);

    // layer 2: BN1+ReLU fused into A staging
    gemm_bn_kernel<1><<<dim3(H2 / BNT, NN / BM), 256, 0, stream>>>(
        pre1, lw2T, lb2, pre2, colsum2, colsq2, scale1, shift1, H2, H1);
    bn_finalize_kernel<<<H2 / 256, 256, 0, stream>>>(colsum2, colsq2, g2, b2, scale2, shift2, H2);

    // layer 3: BN2+ReLU fused into A staging
    gemm_bn_kernel<1><<<dim3(H3 / BNT, NN / BM), 256, 0, stream>>>(
        pre2, lw3T, lb3, pre3, colsum3, colsq3, scale2, shift2, H3, H2);

    // final: inline BN3 finalize + row-sum + FM + bias
    final_kernel<<<NN / 4, 256, 0, stream>>>(
        pre3, colsum3, colsq3, g3, b3, fm_part, bias, out);
}

// Round 5
// 792.547 us; speedup vs baseline: 1.0268x; 1.0268x over previous
//
#include <hip/hip_runtime.h>
#include <stdint.h>
#include <stddef.h>

// ---------------- Problem constants ----------------
#define NN 16384
#define FF 39
#define VV 50000
#define EE 64
#define K1 2496   // FF*EE
#define H1 1024
#define H2 512
#define H3 256
#define BN_EPS 1e-5f

typedef __attribute__((ext_vector_type(8))) short bf16x8;
typedef __attribute__((ext_vector_type(4))) float f32x4;
typedef unsigned short u16;

__device__ __forceinline__ float bf2f(u16 u) {
    unsigned int x = ((unsigned int)u) << 16;
    return __builtin_bit_cast(float, x);
}
__device__ __forceinline__ u16 f2bf(float f) {
    unsigned int x = __builtin_bit_cast(unsigned int, f);
    x += 0x7fffu + ((x >> 16) & 1u);   // round-to-nearest-even
    return (u16)(x >> 16);
}

// Async global->LDS 16B copy: LDS dest = wave-uniform base + lane*16.
__device__ __forceinline__ void async_copy16(const void* gp, void* lp) {
    __builtin_amdgcn_global_load_lds(
        (const __attribute__((address_space(1))) void*)(uintptr_t)gp,
        (__attribute__((address_space(3))) void*)(uintptr_t)lp,
        16, 0, 0);
}

// ---------------- Prep kernel ----------------
// blocks [0, 4096): embedding gather + FM terms (one wave per sample).
//   block 0 additionally zeroes the BN-stat accumulators (replaces memset).
// blocks [4096, 7232): batched weight transpose f32[K][N] -> bf16[N][K].
__global__ __launch_bounds__(256) void prep_kernel(
    const int* __restrict__ Xi, const float* __restrict__ Xv,
    const float* __restrict__ W1, const float* __restrict__ W2,
    u16* __restrict__ deep, float* __restrict__ fm_part,
    const float* __restrict__ lw1, const float* __restrict__ lw2,
    const float* __restrict__ lw3,
    u16* __restrict__ lw1T, u16* __restrict__ lw2T, u16* __restrict__ lw3T,
    float* __restrict__ stats0)
{
    __shared__ float tile[32][33];
    int bid = blockIdx.x;

    if (bid < NN / 4) {
        // ---- embedding + FM path ----
        if (bid == 0) {
            for (int i = threadIdx.x; i < 3584; i += 256) stats0[i] = 0.f;
        }
        int wave = threadIdx.x >> 6, lane = threadIdx.x & 63;
        int n = bid * 4 + wave;

        int   idx_l = 0; float xv_l = 0.f, e1 = 0.f;
        if (lane < FF) {
            idx_l = Xi[n * FF + lane];
            xv_l  = Xv[n * FF + lane];
            e1    = W1[(size_t)lane * VV + idx_l] * xv_l;
        }
        int fq = lane >> 4, eq = lane & 15;
        float s0 = 0.f, s1 = 0.f, s2 = 0.f, s3 = 0.f;
        float q0 = 0.f, q1 = 0.f, q2 = 0.f, q3 = 0.f;
        u16* drow = deep + (size_t)n * K1;

        #pragma unroll
        for (int g = 0; g < 10; ++g) {
            int f = g * 4 + fq;
            bool valid = (f < FF);
            int fs = valid ? f : 0;
            int   idx = __shfl(idx_l, fs);
            float xv  = __shfl(xv_l, fs);
            float4 v4 = make_float4(0.f, 0.f, 0.f, 0.f);
            if (valid)
                v4 = *(const float4*)(W2 + ((size_t)f * VV + idx) * EE + eq * 4);
            v4.x *= xv; v4.y *= xv; v4.z *= xv; v4.w *= xv;
            s0 += v4.x; q0 += v4.x * v4.x;
            s1 += v4.y; q1 += v4.y * v4.y;
            s2 += v4.z; q2 += v4.z * v4.z;
            s3 += v4.w; q3 += v4.w * v4.w;
            if (valid) {
                union { u16 u[4]; uint2 d; } pk;
                pk.u[0] = f2bf(v4.x); pk.u[1] = f2bf(v4.y);
                pk.u[2] = f2bf(v4.z); pk.u[3] = f2bf(v4.w);
                *(uint2*)(drow + f * EE + eq * 4) = pk.d;
            }
        }
        s0 += __shfl_xor(s0, 16); s0 += __shfl_xor(s0, 32);
        s1 += __shfl_xor(s1, 16); s1 += __shfl_xor(s1, 32);
        s2 += __shfl_xor(s2, 16); s2 += __shfl_xor(s2, 32);
        s3 += __shfl_xor(s3, 16); s3 += __shfl_xor(s3, 32);
        q0 += __shfl_xor(q0, 16); q0 += __shfl_xor(q0, 32);
        q1 += __shfl_xor(q1, 16); q1 += __shfl_xor(q1, 32);
        q2 += __shfl_xor(q2, 16); q2 += __shfl_xor(q2, 32);
        q3 += __shfl_xor(q3, 16); q3 += __shfl_xor(q3, 32);

        float fm2 = 0.5f * ((s0 * s0 + s1 * s1 + s2 * s2 + s3 * s3)
                            - (q0 + q1 + q2 + q3));
        float t = e1 + ((fq == 0) ? fm2 : 0.f);
        #pragma unroll
        for (int off = 32; off; off >>= 1) t += __shfl_xor(t, off);
        if (lane == 0) fm_part[n] = t;
        return;
    }

    // ---- transpose path ----
    int tb = bid - NN / 4;
    const float* w; u16* wT; int K, Nc, bx, by;
    if (tb < 2496)      { w = lw1; wT = lw1T; K = K1; Nc = H1; bx = tb & 31; by = tb >> 5; }
    else if (tb < 3008) { tb -= 2496; w = lw2; wT = lw2T; K = H1; Nc = H2; bx = tb & 15; by = tb >> 4; }
    else                { tb -= 3008; w = lw3; wT = lw3T; K = H2; Nc = H3; bx = tb & 7;  by = tb >> 3; }

    int tx = threadIdx.x & 31, ty = threadIdx.x >> 5;
    #pragma unroll
    for (int j = 0; j < 4; ++j) {
        int y = by * 32 + ty + j * 8;
        tile[ty + j * 8][tx] = w[(size_t)y * Nc + bx * 32 + tx];
    }
    __syncthreads();
    int xo = by * 32 + tx;
    #pragma unroll
    for (int j = 0; j < 4; ++j) {
        int yo = bx * 32 + ty + j * 8;
        wT[(size_t)yo * K + xo] = f2bf(tile[tx][ty + j * 8]);
    }
}

#define BM 128
#define BNT 128
#define BK 32

// ============ gemm1: 128x128x32, dbuf, stage-early / drain-late ============
// T3-minimum recipe (guide §5.5, m248v2-verified): double-buffered LDS;
// per K-step issue next tile's global_load_lds FIRST, then ds_read+MFMA on
// the current buffer, then ONE vmcnt(0)+s_barrier at the END — the staging
// flight hides under the MFMA cluster (m97's ~20% pre-compute drain stall
// removed). 32 KiB LDS, 3 blocks/CU (R4's 256²/1-block/CU lockstep regressed;
// this keeps m97's proven occupancy).
__global__ __launch_bounds__(256, 3) void gemm1_kernel(
    const u16* __restrict__ A, const u16* __restrict__ Bt,
    const float* __restrict__ lb, u16* __restrict__ C,
    float* __restrict__ colsum, float* __restrict__ colsq,
    int Nc, int K)
{
    __shared__ __align__(16) short As[2][BM * BK];
    __shared__ __align__(16) short Bs[2][BNT * BK];

    int tid  = threadIdx.x;
    int wave = tid >> 6, lane = tid & 63;
    int wm = wave >> 1, wn = wave & 1;
    int r16 = lane & 15, kq = lane >> 4;

    // XCD-aware swizzle (nwg = 8*128 = 1024, %8 == 0)
    unsigned nwg  = gridDim.x * gridDim.y;
    unsigned orig = blockIdx.y * gridDim.x + blockIdx.x;
    unsigned wg   = (orig & 7u) * (nwg >> 3) + (orig >> 3);
    unsigned bx   = wg % gridDim.x, by = wg / gridDim.x;
    int mBase = by * BM, nBase = bx * BNT;

    int rowA = tid >> 2;
    int ca   = (tid & 3) * 8;
    const u16* gA0 = A  + (size_t)(mBase + rowA) * K + ca;
    const u16* gA1 = gA0 + (size_t)64 * K;
    const u16* gB0 = Bt + (size_t)(nBase + rowA) * K + ca;
    const u16* gB1 = gB0 + (size_t)64 * K;

    f32x4 acc[4][4];
    #pragma unroll
    for (int mi = 0; mi < 4; ++mi)
        #pragma unroll
        for (int ni = 0; ni < 4; ++ni)
            acc[mi][ni] = (f32x4){0.f, 0.f, 0.f, 0.f};

    auto stage = [&](int b) {
        async_copy16(gA0, &As[b][wave * 512]);
        async_copy16(gA1, &As[b][2048 + wave * 512]);
        async_copy16(gB0, &Bs[b][wave * 512]);
        async_copy16(gB1, &Bs[b][2048 + wave * 512]);
        gA0 += BK; gA1 += BK; gB0 += BK; gB1 += BK;
    };

    // prologue: fill buf0, drain, barrier
    stage(0);
    asm volatile("s_waitcnt vmcnt(0)" ::: "memory");
    __builtin_amdgcn_s_barrier();

    const int nt = K / BK;   // 78
    int cur = 0;
    for (int t = 0; t < nt; ++t) {
        if (t + 1 < nt) stage(cur ^ 1);           // issue next tile EARLY
        const short* fA = &As[cur][(wm * 64 + r16) * BK + kq * 8];
        const short* fB = &Bs[cur][(wn * 64 + r16) * BK + kq * 8];
        bf16x8 af[4], bfr[4];
        #pragma unroll
        for (int mi = 0; mi < 4; ++mi)
            af[mi] = *(const bf16x8*)(fA + mi * 16 * BK);
        #pragma unroll
        for (int ni = 0; ni < 4; ++ni)
            bfr[ni] = *(const bf16x8*)(fB + ni * 16 * BK);
        __builtin_amdgcn_s_setprio(1);
        #pragma unroll
        for (int mi = 0; mi < 4; ++mi)
            #pragma unroll
            for (int ni = 0; ni < 4; ++ni)
                acc[mi][ni] = __builtin_amdgcn_mfma_f32_16x16x32_bf16(
                    af[mi], bfr[ni], acc[mi][ni], 0, 0, 0);
        __builtin_amdgcn_s_setprio(0);
        if (t + 1 < nt) {
            asm volatile("s_waitcnt vmcnt(0)" ::: "memory");   // drain LATE
            __builtin_amdgcn_s_barrier();
            cur ^= 1;
        }
    }

    // epilogue: bias, bf16 store (pre-BN), column sum/sumsq partials
    int quad = lane >> 4;
    #pragma unroll
    for (int ni = 0; ni < 4; ++ni) {
        int col = nBase + wn * 64 + ni * 16 + r16;
        float lbv = lb[col];
        float csum = 0.f, csq = 0.f;
        #pragma unroll
        for (int mi = 0; mi < 4; ++mi) {
            int row0 = mBase + wm * 64 + mi * 16 + quad * 4;
            f32x4 v = acc[mi][ni];
            #pragma unroll
            for (int r = 0; r < 4; ++r) {
                float x = v[r] + lbv;
                C[(size_t)(row0 + r) * Nc + col] = f2bf(x);
                csum += x;
                csq  += x * x;
            }
        }
        csum += __shfl_xor(csum, 16); csum += __shfl_xor(csum, 32);
        csq  += __shfl_xor(csq, 16);  csq  += __shfl_xor(csq, 32);
        if (quad == 0) {
            atomicAdd(&colsum[col], csum);
            atomicAdd(&colsq[col],  csq);
        }
    }
}

// ---------- gemm2/3: m97 structure + fused BN-finalize + BN-apply ----------
// Per-block BN finalize at entry: scale/shift for all K input columns
// recomputed into LDS (bit-identical f32 math to the old bn_finalize pass,
// which is hereby eliminated). A is reg-staged: relu(x*sc+sh) -> bf16 -> LDS.
__global__ __launch_bounds__(256, 3) void gemm_bn_kernel(
    const u16* __restrict__ A, const u16* __restrict__ Bt,
    const float* __restrict__ lb, u16* __restrict__ C,
    float* __restrict__ colsum, float* __restrict__ colsq,
    const float* __restrict__ csumA, const float* __restrict__ csqA,
    const float* __restrict__ gA_, const float* __restrict__ bA_,
    int Nc, int K)
{
    __shared__ __align__(16) short As[BM * BK];
    __shared__ __align__(16) short Bs[BNT * BK];
    __shared__ float scS[H1], shS[H1];   // K <= 1024

    int tid  = threadIdx.x;
    int wave = tid >> 6, lane = tid & 63;
    int wm = wave >> 1, wn = wave & 1;

    // fused BN finalize for the input columns (visibility via loop-top sync)
    {
        const float invN = 1.0f / (float)NN;
        for (int c = tid; c < K; c += 256) {
            float mean = csumA[c] * invN;
            float var  = csqA[c] * invN - mean * mean;
            float sc   = gA_[c] * rsqrtf(var + BN_EPS);
            scS[c] = sc;
            shS[c] = bA_[c] - mean * sc;
        }
    }

    unsigned nwg  = gridDim.x * gridDim.y;
    unsigned orig = blockIdx.y * gridDim.x + blockIdx.x;
    unsigned wg   = (orig & 7u) * (nwg >> 3) + (orig >> 3);
    unsigned bx   = wg % gridDim.x, by = wg / gridDim.x;
    int mBase = by * BM, nBase = bx * BNT;

    int rowA = tid >> 2;
    int ca   = (tid & 3) * 8;
    const u16* gA0 = A  + (size_t)(mBase + rowA) * K + ca;
    const u16* gA1 = gA0 + (size_t)64 * K;
    const u16* gB0 = Bt + (size_t)(nBase + rowA) * K + ca;
    const u16* gB1 = gB0 + (size_t)64 * K;

    short* lB0 = Bs + wave * 512;
    short* lB1 = Bs + 2048 + wave * 512;

    f32x4 acc[4][4];
    #pragma unroll
    for (int mi = 0; mi < 4; ++mi)
        #pragma unroll
        for (int ni = 0; ni < 4; ++ni)
            acc[mi][ni] = (f32x4){0.f, 0.f, 0.f, 0.f};

    int r16 = lane & 15, kq = lane >> 4;
    const short* fA = &As[(wm * 64 + r16) * BK + kq * 8];
    const short* fB = &Bs[(wn * 64 + r16) * BK + kq * 8];

    int kcur = ca;
    for (int kiter = K / BK; kiter > 0; --kiter) {
        __syncthreads();   // prior tile consumed; also fences scS/shS init
        {
            int4 ra0 = *(const int4*)gA0;
            int4 ra1 = *(const int4*)gA1;
            async_copy16(gB0, lB0);
            async_copy16(gB1, lB1);
            float sc[8], sh[8];
            #pragma unroll
            for (int j = 0; j < 8; ++j) { sc[j] = scS[kcur + j]; sh[j] = shS[kcur + j]; }
            union { u16 u[8]; int4 d; } in, outp;
            in.d = ra0;
            #pragma unroll
            for (int j = 0; j < 8; ++j)
                outp.u[j] = f2bf(fmaxf(bf2f(in.u[j]) * sc[j] + sh[j], 0.f));
            *(int4*)(As + (size_t)tid * 8) = outp.d;          // rows 0..63
            in.d = ra1;
            #pragma unroll
            for (int j = 0; j < 8; ++j)
                outp.u[j] = f2bf(fmaxf(bf2f(in.u[j]) * sc[j] + sh[j], 0.f));
            *(int4*)(As + 2048 + (size_t)tid * 8) = outp.d;   // rows 64..127
            kcur += BK;
        }
        gA0 += BK; gA1 += BK; gB0 += BK; gB1 += BK;
        __syncthreads();

        bf16x8 af[4], bfr[4];
        #pragma unroll
        for (int mi = 0; mi < 4; ++mi)
            af[mi] = *(const bf16x8*)(fA + mi * 16 * BK);
        #pragma unroll
        for (int ni = 0; ni < 4; ++ni)
            bfr[ni] = *(const bf16x8*)(fB + ni * 16 * BK);
        #pragma unroll
        for (int mi = 0; mi < 4; ++mi)
            #pragma unroll
            for (int ni = 0; ni < 4; ++ni)
                acc[mi][ni] = __builtin_amdgcn_mfma_f32_16x16x32_bf16(
                    af[mi], bfr[ni], acc[mi][ni], 0, 0, 0);
    }

    int quad = lane >> 4;
    #pragma unroll
    for (int ni = 0; ni < 4; ++ni) {
        int col = nBase + wn * 64 + ni * 16 + r16;
        float lbv = lb[col];
        float csum = 0.f, csq = 0.f;
        #pragma unroll
        for (int mi = 0; mi < 4; ++mi) {
            int row0 = mBase + wm * 64 + mi * 16 + quad * 4;
            f32x4 v = acc[mi][ni];
            #pragma unroll
            for (int r = 0; r < 4; ++r) {
                float x = v[r] + lbv;
                C[(size_t)(row0 + r) * Nc + col] = f2bf(x);
                csum += x;
                csq  += x * x;
            }
        }
        csum += __shfl_xor(csum, 16); csum += __shfl_xor(csum, 32);
        csq  += __shfl_xor(csq, 16);  csq  += __shfl_xor(csq, 32);
        if (quad == 0) {
            atomicAdd(&colsum[col], csum);
            atomicAdd(&colsq[col],  csq);
        }
    }
}

// ------- Final: inline BN finalize (layer3) + ReLU + row sum + FM + bias ----
__global__ __launch_bounds__(256) void final_kernel(
    const u16* __restrict__ pre3,
    const float* __restrict__ colsum, const float* __restrict__ colsq,
    const float* __restrict__ g, const float* __restrict__ b,
    const float* __restrict__ fm_part,
    const float* __restrict__ bias, float* __restrict__ out)
{
    int wave = threadIdx.x >> 6, lane = threadIdx.x & 63;
    int n = blockIdx.x * 4 + wave;
    const float invN = 1.0f / (float)NN;
    float s = 0.f;
    #pragma unroll
    for (int q = 0; q < 4; ++q) {
        int c = q * 64 + lane;
        float mean = colsum[c] * invN;
        float var  = colsq[c] * invN - mean * mean;
        float sc   = g[c] * rsqrtf(var + BN_EPS);
        float sh   = b[c] - mean * sc;
        float x = bf2f(pre3[(size_t)n * H3 + c]);
        s += fmaxf(x * sc + sh, 0.f);
    }
    #pragma unroll
    for (int off = 32; off; off >>= 1) s += __shfl_xor(s, off);
    if (lane == 0) out[n] = s + fm_part[n] + bias[0];
}

// ---------------- Host launcher ----------------
extern "C" void kernel_launch(void* const* d_in, const int* in_sizes, int n_in,
                              void* d_out, int out_size, void* d_ws, size_t ws_size,
                              hipStream_t stream)
{
    const int*   Xi   = (const int*)d_in[0];
    const float* Xv   = (const float*)d_in[1];
    const float* W1   = (const float*)d_in[2];
    const float* W2   = (const float*)d_in[3];
    const float* bias = (const float*)d_in[4];
    const float* lw1  = (const float*)d_in[5];
    const float* lb1  = (const float*)d_in[6];
    const float* g1   = (const float*)d_in[7];
    const float* b1   = (const float*)d_in[8];
    const float* lw2  = (const float*)d_in[9];
    const float* lb2  = (const float*)d_in[10];
    const float* g2   = (const float*)d_in[11];
    const float* b2   = (const float*)d_in[12];
    const float* lw3  = (const float*)d_in[13];
    const float* lb3  = (const float*)d_in[14];
    const float* g3   = (const float*)d_in[15];
    const float* b3   = (const float*)d_in[16];
    float* out = (float*)d_out;
    char*  ws  = (char*)d_ws;

    // ---- workspace layout (bytes, 256-aligned) ----
    float* fm_part = (float*)(ws + 0);                  // 65536
    float* stats0  = (float*)(ws + 65536);              // colsum/colsq block
    float* colsum1 = (float*)(ws + 65536);
    float* colsq1  = (float*)(ws + 69632);
    float* colsum2 = (float*)(ws + 73728);
    float* colsq2  = (float*)(ws + 75776);
    float* colsum3 = (float*)(ws + 77824);
    float* colsq3  = (float*)(ws + 78848);
    u16* lw1T = (u16*)(ws + 94208);                     // 5,111,808
    u16* lw2T = (u16*)(ws + 5206016);                   // 1,048,576
    u16* lw3T = (u16*)(ws + 6254592);                   // 262,144
    u16* pre1 = (u16*)(ws + 6516736);                   // 33,554,432
    u16* deep = (u16*)(ws + 40071168);                  // 81,788,928
    u16* pre2 = (u16*)(ws + 40071168);                  // reuse deep region
    u16* pre3 = (u16*)(ws + 56848384);

    // prep: embed+FM (4096 blocks) | 3 weight transposes (3136) | stat zeroing
    prep_kernel<<<NN / 4 + 3136, 256, 0, stream>>>(
        Xi, Xv, W1, W2, deep, fm_part, lw1, lw2, lw3, lw1T, lw2T, lw3T, stats0);

    // layer 1: dbuf stage-early/drain-late 128^2 (grid 8 x 128)
    gemm1_kernel<<<dim3(H1 / BNT, NN / BM), 256, 0, stream>>>(
        deep, lw1T, lb1, pre1, colsum1, colsq1, H1, K1);

    // layer 2: per-block BN1 finalize + BN1+ReLU fused into A staging
    gemm_bn_kernel<<<dim3(H2 / BNT, NN / BM), 256, 0, stream>>>(
        pre1, lw2T, lb2, pre2, colsum2, colsq2,
        colsum1, colsq1, g1, b1, H2, H1);

    // layer 3: per-block BN2 finalize + BN2+ReLU fused into A staging
    gemm_bn_kernel<<<dim3(H3 / BNT, NN / BM), 256, 0, stream>>>(
        pre2, lw3T, lb3, pre3, colsum3, colsq3,
        colsum2, colsq2, g2, b2, H3, H2);

    // final: inline BN3 finalize + row-sum + FM + bias
    final_kernel<<<NN / 4, 256, 0, stream>>>(
        pre3, colsum3, colsq3, g3, b3, fm_part, bias, out);
}